// Round 8
// baseline (280.145 us; speedup 1.0000x reference)
//
#include <hip/hip_runtime.h>
#include <hip/hip_bf16.h>

#define NNODES 50000
#define NEDGES 1600000
#define NBIN2  1564     // ceil(50000/32) destination bins of 32 nodes
#define CAPB2  1440     // per-bin total capacity; mean 1024, sigma ~32 (+13 sigma)
#define SCAP   320      // per-(xcd,bin) segment capacity; mean 128, sigma ~11
#define OVFCAP 65536    // overflow list (expected 0 entries)
#define BCHUNK 2000
#define NBBLK  800      // NBBLK * BCHUNK == NEDGES
#define HALFSZ (NNODES * 32)   // one feature-half table: 50000 x 32 bf16 = 3.2 MB

__device__ __forceinline__ float bf2f(unsigned short u) {
    union { unsigned int i; float f; } x; x.i = ((unsigned int)u) << 16; return x.f;
}

// ---------------------------------------------------------------------------
// 1) Round-2 binning body, 32-node bins (round-7). Packs r | (c&31)<<16 |
//    bin<<21. Per-XCD sub-segments -> no cross-XCD line ping-pong; no
//    per-edge global atomics.
__global__ __launch_bounds__(256) void k_bin(const int* __restrict__ edges,
                                             int* __restrict__ bincur,
                                             int* __restrict__ ovfcnt,
                                             int* __restrict__ ovf,
                                             int* __restrict__ binned) {
    __shared__ int pk[BCHUNK];
    __shared__ int hist[NBIN2];
    __shared__ int gbase[NBIN2];
    __shared__ int lcnt[NBIN2];
    int t = threadIdx.x;
    int e0 = blockIdx.x * BCHUNK;
    unsigned xcd;
    asm volatile("s_getreg_b32 %0, hwreg(HW_REG_XCC_ID)" : "=s"(xcd));
    xcd &= 7;
    for (int i = t; i < NBIN2; i += 256) { hist[i] = 0; lcnt[i] = 0; }
    __syncthreads();
    for (int i = t * 4; i < BCHUNK; i += 1024) {
        int4 r4 = *(const int4*)&edges[e0 + i];
        int4 c4 = *(const int4*)&edges[NEDGES + e0 + i];
        int b0 = c4.x >> 5, b1 = c4.y >> 5, b2 = c4.z >> 5, b3 = c4.w >> 5;
        pk[i + 0] = r4.x | ((c4.x & 31) << 16) | (b0 << 21);
        pk[i + 1] = r4.y | ((c4.y & 31) << 16) | (b1 << 21);
        pk[i + 2] = r4.z | ((c4.z & 31) << 16) | (b2 << 21);
        pk[i + 3] = r4.w | ((c4.w & 31) << 16) | (b3 << 21);
        atomicAdd(&hist[b0], 1);
        atomicAdd(&hist[b1], 1);
        atomicAdd(&hist[b2], 1);
        atomicAdd(&hist[b3], 1);
    }
    __syncthreads();
    for (int i = t; i < NBIN2; i += 256) {
        int h = hist[i];
        gbase[i] = (h > 0) ? atomicAdd(&bincur[xcd * NBIN2 + i], h) : 0;
    }
    __syncthreads();
    for (int i = t; i < BCHUNK; i += 256) {
        int v = pk[i];
        int bin = ((unsigned)v) >> 21;
        int p = gbase[bin] + atomicAdd(&lcnt[bin], 1);
        if (p < SCAP) {
            binned[(xcd * NBIN2 + bin) * SCAP + p] = v;
        } else {
            int op = atomicAdd(ovfcnt, 1);
            if (op < OVFCAP) ovf[op] = v;
        }
    }
}

// ---------------------------------------------------------------------------
// 2) Per-bin LDS counting sort (round-7 body). Only change: x0s is written
//    as two contiguous half-tables [half][n][32] so each gather pass has a
//    3.2 MB working set that fits a 4 MB per-XCD L2.
__global__ __launch_bounds__(256) void k_sortbin(const int* __restrict__ bincur,
                                                 const int* __restrict__ binned,
                                                 const int* __restrict__ ovfcnt,
                                                 const int* __restrict__ ovf,
                                                 const float* __restrict__ x,
                                                 int* __restrict__ rowptr,
                                                 int* __restrict__ cntn,
                                                 float* __restrict__ dinv,
                                                 unsigned short* __restrict__ x0s,
                                                 int* __restrict__ csr) {
    __shared__ int h[32];
    __shared__ int off[32];
    __shared__ int cur[32];
    __shared__ float dv[32];
    __shared__ int slen[8];
    __shared__ int stage[CAPB2];
    int t = threadIdx.x, bin = blockIdx.x;
    int wave = t >> 6, lane = t & 63;
    int n0 = bin * 32;
    // hoisted x loads (independent of everything below)
    float xv[8];
    #pragma unroll
    for (int k = 0; k < 8; ++k) {
        int n = n0 + wave + 4 * k;
        xv[k] = (n < NNODES) ? x[n * 256 + lane] : 0.0f;
    }
    if (t < 32) h[t] = 0;
    if (t < 8) slen[t] = min(bincur[t * NBIN2 + bin], SCAP);
    __syncthreads();
    int novf = ovfcnt[0];
    // histogram: two segments concurrently (t>>7 selects the segment)
    for (int sp = 0; sp < 8; sp += 2) {
        int s = sp + (t >> 7);
        int tl = t & 127;
        int len = slen[s];
        const int* __restrict__ bb = binned + (s * NBIN2 + bin) * SCAP;
        for (int e = tl; e < len; e += 128)
            atomicAdd(&h[(bb[e] >> 16) & 31], 1);
    }
    for (int e = t; e < novf; e += 256) {
        int v = ovf[e];
        if (((unsigned)v >> 21) == (unsigned)bin) atomicAdd(&h[(v >> 16) & 31], 1);
    }
    __syncthreads();
    if (t < 32) {
        int v = h[t];
        int inc = v;
        #pragma unroll
        for (int d = 1; d < 32; d <<= 1) {
            int u = __shfl_up(inc, d);
            if (lane >= d) inc += u;
        }
        int ex = inc - v;
        off[t] = ex;
        cur[t] = ex;
        float dc = rsqrtf((float)(v + 1));
        dv[t] = dc;
        int n = n0 + t;
        if (n < NNODES) {
            dinv[n] = dc;
            rowptr[n] = bin * CAPB2 + ex;
            cntn[n] = v;
        }
    }
    __syncthreads();
    // placement: same two-segment concurrency
    for (int sp = 0; sp < 8; sp += 2) {
        int s = sp + (t >> 7);
        int tl = t & 127;
        int len = slen[s];
        const int* __restrict__ bb = binned + (s * NBIN2 + bin) * SCAP;
        for (int e = tl; e < len; e += 128) {
            int v = bb[e];
            int p = atomicAdd(&cur[(v >> 16) & 31], 1);
            if (p < CAPB2) stage[p] = v & 0xFFFF;
        }
    }
    for (int e = t; e < novf; e += 256) {
        int v = ovf[e];
        if (((unsigned)v >> 21) == (unsigned)bin) {
            int p = atomicAdd(&cur[(v >> 16) & 31], 1);
            if (p < CAPB2) stage[p] = v & 0xFFFF;
        }
    }
    __syncthreads();
    int total = min(off[31] + h[31], CAPB2);
    for (int e = t; e < total; e += 256)
        csr[bin * CAPB2 + e] = stage[e];
    // pre-scaled bf16 rows into the two half-tables: [lane>>5][n][lane&31]
    #pragma unroll
    for (int k = 0; k < 8; ++k) {
        int i = wave + 4 * k;
        int n = n0 + i;
        if (n < NNODES) {
            __hip_bfloat16 v = __float2bfloat16(xv[k] * dv[i]);
            x0s[(lane >> 5) * HALFSZ + n * 32 + (lane & 31)] = *(unsigned short*)&v;
        }
    }
}

// ---------------------------------------------------------------------------
// 3) Half-feature gather pass. Working set = one 3.2 MB half-table ->
//    L2-resident per XCD (the round-8 lever). Wave = 2 nodes x 32 lanes;
//    __shfl(...,32) broadcasts within each half; 64 B coalesced row loads;
//    csr via nontemporal load and agg via nontemporal store so the streams
//    don't evict the resident table. Two sequential launches (pass 0, 1).
__global__ __launch_bounds__(256) void k_gather(const unsigned short* __restrict__ x0s,
                                                const int* __restrict__ rowptr,
                                                const int* __restrict__ cntn,
                                                const float* __restrict__ dinv,
                                                const int* __restrict__ csr,
                                                float* __restrict__ agg,
                                                int pass) {
    const unsigned short* __restrict__ xh = x0s + pass * HALFSZ;
    int t = threadIdx.x, lane = t & 63, w = t >> 6;
    int half = lane >> 5, fi = lane & 31;
    int n = (blockIdx.x * 4 + w) * 2 + half;   // 6250 * 4 * 2 = 50000 exactly
    int start = rowptr[n], len = cntn[n];
    float acc0 = bf2f(xh[n * 32 + fi]);        // self-loop (pre-scaled)
    float acc1 = 0.0f;
    for (int base = 0; base < len; base += 32) {
        int m = min(len - base, 32);
        int idx = (fi < m) ? __builtin_nontemporal_load(&csr[start + base + fi]) : 0;
        int j = 0;
        for (; j + 8 <= m; j += 8) {
            int r0 = __shfl(idx, j + 0, 32), r1 = __shfl(idx, j + 1, 32);
            int r2 = __shfl(idx, j + 2, 32), r3 = __shfl(idx, j + 3, 32);
            int r4 = __shfl(idx, j + 4, 32), r5 = __shfl(idx, j + 5, 32);
            int r6 = __shfl(idx, j + 6, 32), r7 = __shfl(idx, j + 7, 32);
            float f0 = bf2f(xh[r0 * 32 + fi]);
            float f1 = bf2f(xh[r1 * 32 + fi]);
            float f2 = bf2f(xh[r2 * 32 + fi]);
            float f3 = bf2f(xh[r3 * 32 + fi]);
            float f4 = bf2f(xh[r4 * 32 + fi]);
            float f5 = bf2f(xh[r5 * 32 + fi]);
            float f6 = bf2f(xh[r6 * 32 + fi]);
            float f7 = bf2f(xh[r7 * 32 + fi]);
            acc0 += (f0 + f1) + (f2 + f3);
            acc1 += (f4 + f5) + (f6 + f7);
        }
        for (; j < m; ++j) {
            int r = __shfl(idx, j, 32);
            acc0 += bf2f(xh[r * 32 + fi]);
        }
    }
    float v = (acc0 + acc1) * dinv[n];
    __builtin_nontemporal_store(v, &agg[n * 64 + pass * 32 + fi]);
}

// ---------------------------------------------------------------------------
// 4) per-head 64x64 linear + bias + relu, dual store. 2000 blocks x 25 nodes
//    (W L2 traffic 128 MB; stores at the 6.3 TB/s write floor ~33 us).
__global__ __launch_bounds__(256) void k_gemm(const float* __restrict__ agg,
                                              const float* __restrict__ W,
                                              const float* __restrict__ b,
                                              float* __restrict__ out0,
                                              float* __restrict__ out1) {
    int t = threadIdx.x;
    int h = t >> 6, o = t & 63;
    float wreg[64];
    #pragma unroll
    for (int f = 0; f < 64; ++f) wreg[f] = W[h * 4096 + f * 64 + o];
    float bias = b[t];
    int n0 = blockIdx.x * 25;   // 2000 * 25 = 50000 exactly
    for (int i = 0; i < 25; ++i) {
        int n = n0 + i;
        const float* __restrict__ arow = agg + n * 64;   // block-uniform address
        float acc = bias;
        #pragma unroll
        for (int f = 0; f < 64; ++f) acc = fmaf(arow[f], wreg[f], acc);
        float v = fmaxf(acc, 0.0f);
        __builtin_nontemporal_store(v, &out0[n * 256 + t]);
        __builtin_nontemporal_store(v, &out1[n * 256 + t]);
    }
}

// ---------------------------------------------------------------------------

extern "C" void kernel_launch(void* const* d_in, const int* in_sizes, int n_in,
                              void* d_out, int out_size, void* d_ws, size_t ws_size,
                              hipStream_t stream) {
    const float* x     = (const float*)d_in[0];   // (50000, 256) f32
    const int*   edges = (const int*)d_in[1];     // (2, 1600000) int32
    const float* W     = (const float*)d_in[2];   // (4, 64, 64) f32
    const float* b     = (const float*)d_in[3];   // (4, 64) f32

    float* out0 = (float*)d_out;                   // x_cat (50000,256)
    float* out1 = out0 + (size_t)NNODES * 256;     // heads (50000,4,64) — same values

    // workspace layout (512B-aligned sections)
    char* ws = (char*)d_ws;
    int*            bincur = (int*)(ws + 0);              //     50,048 B (8 x 1564)
    int*            ovfcnt = (int*)(ws + 50176);          //          4 B
    int*            ovf    = (int*)(ws + 50688);          //    262,144 B
    float*          dinv   = (float*)(ws + 312832);       //    200,000 B
    int*            rowptr = (int*)(ws + 513024);         //    200,000 B
    int*            cntn   = (int*)(ws + 713216);         //    200,000 B
    int*            binned = (int*)(ws + 913408);         // 16,015,360 B (8 x 1564 x 320)
    int*            csr    = (int*)(ws + 16928768);       //  9,008,640 B (1564 x 1440)
    unsigned short* x0s    = (unsigned short*)(ws + 25937408);  // 6,400,000 B (2 x 50000 x 32)
    float*          agg    = (float*)(ws + 32337408);     // 12,800,000 B  (total ~45.1 MB)

    hipMemsetAsync(ws, 0, 50180, stream);   // bincur + ovfcnt
    k_bin    <<<NBBLK, 256, 0, stream>>>(edges, bincur, ovfcnt, ovf, binned);
    k_sortbin<<<NBIN2, 256, 0, stream>>>(bincur, binned, ovfcnt, ovf, x, rowptr, cntn, dinv, x0s, csr);
    k_gather <<<6250, 256, 0, stream>>>(x0s, rowptr, cntn, dinv, csr, agg, 0);
    k_gather <<<6250, 256, 0, stream>>>(x0s, rowptr, cntn, dinv, csr, agg, 1);
    k_gemm   <<<2000, 256, 0, stream>>>(agg, W, b, out0, out1);
}

// Round 9
// 239.095 us; speedup vs baseline: 1.1717x; 1.1717x over previous
//
#include <hip/hip_runtime.h>
#include <hip/hip_bf16.h>

#define NNODES 50000
#define NEDGES 1600000
#define NBIN2  1564     // ceil(50000/32) destination bins of 32 nodes
#define CAPB2  1440     // per-bin total capacity; mean 1024, sigma ~32 (+13 sigma)
#define SCAP   320      // per-(xcd,bin) segment capacity; mean 128, sigma ~11
#define OVFCAP 65536    // overflow list (expected 0 entries)
#define BCHUNK 2000
#define NBBLK  800      // NBBLK * BCHUNK == NEDGES

__device__ __forceinline__ float bf2f(unsigned short u) {
    union { unsigned int i; float f; } x; x.i = ((unsigned int)u) << 16; return x.f;
}

// ---------------------------------------------------------------------------
// 1) Round-2 binning body, 32-node bins (round-7, measured-best). Packs
//    r | (c&31)<<16 | bin<<21. Per-XCD sub-segments -> no cross-XCD line
//    ping-pong; no per-edge global atomics.
__global__ __launch_bounds__(256) void k_bin(const int* __restrict__ edges,
                                             int* __restrict__ bincur,
                                             int* __restrict__ ovfcnt,
                                             int* __restrict__ ovf,
                                             int* __restrict__ binned) {
    __shared__ int pk[BCHUNK];
    __shared__ int hist[NBIN2];
    __shared__ int gbase[NBIN2];
    __shared__ int lcnt[NBIN2];
    int t = threadIdx.x;
    int e0 = blockIdx.x * BCHUNK;
    unsigned xcd;
    asm volatile("s_getreg_b32 %0, hwreg(HW_REG_XCC_ID)" : "=s"(xcd));
    xcd &= 7;
    for (int i = t; i < NBIN2; i += 256) { hist[i] = 0; lcnt[i] = 0; }
    __syncthreads();
    for (int i = t * 4; i < BCHUNK; i += 1024) {
        int4 r4 = *(const int4*)&edges[e0 + i];
        int4 c4 = *(const int4*)&edges[NEDGES + e0 + i];
        int b0 = c4.x >> 5, b1 = c4.y >> 5, b2 = c4.z >> 5, b3 = c4.w >> 5;
        pk[i + 0] = r4.x | ((c4.x & 31) << 16) | (b0 << 21);
        pk[i + 1] = r4.y | ((c4.y & 31) << 16) | (b1 << 21);
        pk[i + 2] = r4.z | ((c4.z & 31) << 16) | (b2 << 21);
        pk[i + 3] = r4.w | ((c4.w & 31) << 16) | (b3 << 21);
        atomicAdd(&hist[b0], 1);
        atomicAdd(&hist[b1], 1);
        atomicAdd(&hist[b2], 1);
        atomicAdd(&hist[b3], 1);
    }
    __syncthreads();
    for (int i = t; i < NBIN2; i += 256) {
        int h = hist[i];
        gbase[i] = (h > 0) ? atomicAdd(&bincur[xcd * NBIN2 + i], h) : 0;
    }
    __syncthreads();
    for (int i = t; i < BCHUNK; i += 256) {
        int v = pk[i];
        int bin = ((unsigned)v) >> 21;
        int p = gbase[bin] + atomicAdd(&lcnt[bin], 1);
        if (p < SCAP) {
            binned[(xcd * NBIN2 + bin) * SCAP + p] = v;
        } else {
            int op = atomicAdd(ovfcnt, 1);
            if (op < OVFCAP) ovf[op] = v;
        }
    }
}

// ---------------------------------------------------------------------------
// 2) Per-bin LDS counting sort (round-7 body, unchanged). Fused outputs:
//    dinv, rowptr/cntn, pre-scaled bf16 x0s (flat [n][64] ushort layout,
//    128B-aligned rows), node-contiguous csr.
__global__ __launch_bounds__(256) void k_sortbin(const int* __restrict__ bincur,
                                                 const int* __restrict__ binned,
                                                 const int* __restrict__ ovfcnt,
                                                 const int* __restrict__ ovf,
                                                 const float* __restrict__ x,
                                                 int* __restrict__ rowptr,
                                                 int* __restrict__ cntn,
                                                 float* __restrict__ dinv,
                                                 unsigned short* __restrict__ x0s,
                                                 int* __restrict__ csr) {
    __shared__ int h[32];
    __shared__ int off[32];
    __shared__ int cur[32];
    __shared__ float dv[32];
    __shared__ int slen[8];
    __shared__ int stage[CAPB2];
    int t = threadIdx.x, bin = blockIdx.x;
    int wave = t >> 6, lane = t & 63;
    int n0 = bin * 32;
    // hoisted x loads (independent of everything below)
    float xv[8];
    #pragma unroll
    for (int k = 0; k < 8; ++k) {
        int n = n0 + wave + 4 * k;
        xv[k] = (n < NNODES) ? x[n * 256 + lane] : 0.0f;
    }
    if (t < 32) h[t] = 0;
    if (t < 8) slen[t] = min(bincur[t * NBIN2 + bin], SCAP);
    __syncthreads();
    int novf = ovfcnt[0];
    // histogram: two segments concurrently (t>>7 selects the segment)
    for (int sp = 0; sp < 8; sp += 2) {
        int s = sp + (t >> 7);
        int tl = t & 127;
        int len = slen[s];
        const int* __restrict__ bb = binned + (s * NBIN2 + bin) * SCAP;
        for (int e = tl; e < len; e += 128)
            atomicAdd(&h[(bb[e] >> 16) & 31], 1);
    }
    for (int e = t; e < novf; e += 256) {
        int v = ovf[e];
        if (((unsigned)v >> 21) == (unsigned)bin) atomicAdd(&h[(v >> 16) & 31], 1);
    }
    __syncthreads();
    if (t < 32) {
        int v = h[t];
        int inc = v;
        #pragma unroll
        for (int d = 1; d < 32; d <<= 1) {
            int u = __shfl_up(inc, d);
            if (lane >= d) inc += u;
        }
        int ex = inc - v;
        off[t] = ex;
        cur[t] = ex;
        float dc = rsqrtf((float)(v + 1));
        dv[t] = dc;
        int n = n0 + t;
        if (n < NNODES) {
            dinv[n] = dc;
            rowptr[n] = bin * CAPB2 + ex;
            cntn[n] = v;
        }
    }
    __syncthreads();
    // placement: same two-segment concurrency
    for (int sp = 0; sp < 8; sp += 2) {
        int s = sp + (t >> 7);
        int tl = t & 127;
        int len = slen[s];
        const int* __restrict__ bb = binned + (s * NBIN2 + bin) * SCAP;
        for (int e = tl; e < len; e += 128) {
            int v = bb[e];
            int p = atomicAdd(&cur[(v >> 16) & 31], 1);
            if (p < CAPB2) stage[p] = v & 0xFFFF;
        }
    }
    for (int e = t; e < novf; e += 256) {
        int v = ovf[e];
        if (((unsigned)v >> 21) == (unsigned)bin) {
            int p = atomicAdd(&cur[(v >> 16) & 31], 1);
            if (p < CAPB2) stage[p] = v & 0xFFFF;
        }
    }
    __syncthreads();
    int total = min(off[31] + h[31], CAPB2);
    for (int e = t; e < total; e += 256)
        csr[bin * CAPB2 + e] = stage[e];
    // pre-scaled bf16 rows from the hoisted registers
    #pragma unroll
    for (int k = 0; k < 8; ++k) {
        int i = wave + 4 * k;
        int n = n0 + i;
        if (n < NNODES) {
            __hip_bfloat16 v = __float2bfloat16(xv[k] * dv[i]);
            x0s[n * 64 + lane] = *(unsigned short*)&v;
        }
    }
}

// ---------------------------------------------------------------------------
// 3) Per-node gather, TWO ROWS PER LOAD INSTRUCTION (round-9 lever).
//    Round-8 evidence: gather cost tracks VMEM instruction count, not bytes
//    (64B-row split doubled instructions at same bytes -> +35 us). So go the
//    other way: read x0s as uint (2 bf16/lane); lanes 0-31 load row ra,
//    lanes 32-63 load row rb -> one instruction fetches 256B = 2 rows.
//    Row-load instructions: 1.6M -> 0.8M. Each lane accumulates feature pair
//    (2*fi, 2*fi+1) over its half's rows; one shfl_xor(32) merges halves;
//    lanes 0-31 store float2. Wave = node, 50K waves, full occupancy.
__global__ __launch_bounds__(256) void k_gather(const unsigned short* __restrict__ x0s,
                                                const int* __restrict__ rowptr,
                                                const int* __restrict__ cntn,
                                                const float* __restrict__ dinv,
                                                const int* __restrict__ csr,
                                                float* __restrict__ agg) {
    const unsigned int* __restrict__ xu = (const unsigned int*)x0s;  // [n][32] pairs
    int wave = threadIdx.x >> 6, lane = threadIdx.x & 63;
    int half = lane >> 5, fi = lane & 31;
    int n = blockIdx.x * 4 + wave;          // 12500 * 4 = 50000 exactly
    int start = rowptr[n], len = cntn[n];
    // self-loop (pre-scaled): counted once, by half 0
    unsigned int sv = xu[n * 32 + fi];
    float acc0 = 0.0f, acc1 = 0.0f;
    if (half == 0) { acc0 = bf2f((unsigned short)sv); acc1 = bf2f((unsigned short)(sv >> 16)); }
    for (int base = 0; base < len; base += 64) {
        int m = min(len - base, 64);
        int idx = (lane < m) ? csr[start + base + lane] : 0;  // one coalesced load
        int j = 0;
        for (; j + 16 <= m; j += 16) {
            // 8 paired loads = 16 rows in flight
            int ra0 = __shfl(idx, j + 0),  rb0 = __shfl(idx, j + 1);
            int ra1 = __shfl(idx, j + 2),  rb1 = __shfl(idx, j + 3);
            int ra2 = __shfl(idx, j + 4),  rb2 = __shfl(idx, j + 5);
            int ra3 = __shfl(idx, j + 6),  rb3 = __shfl(idx, j + 7);
            int ra4 = __shfl(idx, j + 8),  rb4 = __shfl(idx, j + 9);
            int ra5 = __shfl(idx, j + 10), rb5 = __shfl(idx, j + 11);
            int ra6 = __shfl(idx, j + 12), rb6 = __shfl(idx, j + 13);
            int ra7 = __shfl(idx, j + 14), rb7 = __shfl(idx, j + 15);
            unsigned int u0 = xu[(half ? rb0 : ra0) * 32 + fi];
            unsigned int u1 = xu[(half ? rb1 : ra1) * 32 + fi];
            unsigned int u2 = xu[(half ? rb2 : ra2) * 32 + fi];
            unsigned int u3 = xu[(half ? rb3 : ra3) * 32 + fi];
            unsigned int u4 = xu[(half ? rb4 : ra4) * 32 + fi];
            unsigned int u5 = xu[(half ? rb5 : ra5) * 32 + fi];
            unsigned int u6 = xu[(half ? rb6 : ra6) * 32 + fi];
            unsigned int u7 = xu[(half ? rb7 : ra7) * 32 + fi];
            acc0 += (bf2f((unsigned short)u0) + bf2f((unsigned short)u1))
                  + (bf2f((unsigned short)u2) + bf2f((unsigned short)u3));
            acc1 += (bf2f((unsigned short)(u0 >> 16)) + bf2f((unsigned short)(u1 >> 16)))
                  + (bf2f((unsigned short)(u2 >> 16)) + bf2f((unsigned short)(u3 >> 16)));
            acc0 += (bf2f((unsigned short)u4) + bf2f((unsigned short)u5))
                  + (bf2f((unsigned short)u6) + bf2f((unsigned short)u7));
            acc1 += (bf2f((unsigned short)(u4 >> 16)) + bf2f((unsigned short)(u5 >> 16)))
                  + (bf2f((unsigned short)(u6 >> 16)) + bf2f((unsigned short)(u7 >> 16)));
        }
        for (; j + 2 <= m; j += 2) {
            int ra = __shfl(idx, j), rb = __shfl(idx, j + 1);
            unsigned int u = xu[(half ? rb : ra) * 32 + fi];
            acc0 += bf2f((unsigned short)u);
            acc1 += bf2f((unsigned short)(u >> 16));
        }
        if (j < m) {   // odd leftover row: half 0 only
            int r = __shfl(idx, j);
            unsigned int u = xu[r * 32 + fi];
            if (half == 0) {
                acc0 += bf2f((unsigned short)u);
                acc1 += bf2f((unsigned short)(u >> 16));
            }
        }
    }
    // merge halves (lane l <-> l^32 hold the same feature pair)
    acc0 += __shfl_xor(acc0, 32);
    acc1 += __shfl_xor(acc1, 32);
    if (half == 0) {
        float dc = dinv[n];
        float2 v = make_float2(acc0 * dc, acc1 * dc);
        *(float2*)&agg[n * 64 + 2 * fi] = v;
    }
}

// ---------------------------------------------------------------------------
// 4) per-head 64x64 linear + bias + relu, dual store (round-7: 2000 x 25,
//    write-floor-bound ~33 us).
__global__ __launch_bounds__(256) void k_gemm(const float* __restrict__ agg,
                                              const float* __restrict__ W,
                                              const float* __restrict__ b,
                                              float* __restrict__ out0,
                                              float* __restrict__ out1) {
    int t = threadIdx.x;
    int h = t >> 6, o = t & 63;
    float wreg[64];
    #pragma unroll
    for (int f = 0; f < 64; ++f) wreg[f] = W[h * 4096 + f * 64 + o];
    float bias = b[t];
    int n0 = blockIdx.x * 25;   // 2000 * 25 = 50000 exactly
    for (int i = 0; i < 25; ++i) {
        int n = n0 + i;
        const float* __restrict__ arow = agg + n * 64;   // block-uniform address
        float acc = bias;
        #pragma unroll
        for (int f = 0; f < 64; ++f) acc = fmaf(arow[f], wreg[f], acc);
        float v = fmaxf(acc, 0.0f);
        __builtin_nontemporal_store(v, &out0[n * 256 + t]);
        __builtin_nontemporal_store(v, &out1[n * 256 + t]);
    }
}

// ---------------------------------------------------------------------------

extern "C" void kernel_launch(void* const* d_in, const int* in_sizes, int n_in,
                              void* d_out, int out_size, void* d_ws, size_t ws_size,
                              hipStream_t stream) {
    const float* x     = (const float*)d_in[0];   // (50000, 256) f32
    const int*   edges = (const int*)d_in[1];     // (2, 1600000) int32
    const float* W     = (const float*)d_in[2];   // (4, 64, 64) f32
    const float* b     = (const float*)d_in[3];   // (4, 64) f32

    float* out0 = (float*)d_out;                   // x_cat (50000,256)
    float* out1 = out0 + (size_t)NNODES * 256;     // heads (50000,4,64) — same values

    // workspace layout (512B-aligned sections)
    char* ws = (char*)d_ws;
    int*            bincur = (int*)(ws + 0);              //     50,048 B (8 x 1564)
    int*            ovfcnt = (int*)(ws + 50176);          //          4 B
    int*            ovf    = (int*)(ws + 50688);          //    262,144 B
    float*          dinv   = (float*)(ws + 312832);       //    200,000 B
    int*            rowptr = (int*)(ws + 513024);         //    200,000 B
    int*            cntn   = (int*)(ws + 713216);         //    200,000 B
    int*            binned = (int*)(ws + 913408);         // 16,015,360 B (8 x 1564 x 320)
    int*            csr    = (int*)(ws + 16928768);       //  9,008,640 B (1564 x 1440)
    unsigned short* x0s    = (unsigned short*)(ws + 25937408);  // 6,400,000 B
    float*          agg    = (float*)(ws + 32337408);     // 12,800,000 B  (total ~45.1 MB)

    hipMemsetAsync(ws, 0, 50180, stream);   // bincur + ovfcnt
    k_bin    <<<NBBLK, 256, 0, stream>>>(edges, bincur, ovfcnt, ovf, binned);
    k_sortbin<<<NBIN2, 256, 0, stream>>>(bincur, binned, ovfcnt, ovf, x, rowptr, cntn, dinv, x0s, csr);
    k_gather <<<NNODES / 4, 256, 0, stream>>>(x0s, rowptr, cntn, dinv, csr, agg);
    k_gemm   <<<2000, 256, 0, stream>>>(agg, W, b, out0, out1);
}